// Round 1
// 2167.623 us; speedup vs baseline: 2.2927x; 2.2927x over previous
//
#include <hip/hip_runtime.h>

// Encoder: x[B,T] int32, hidden[B,U], emb[V,E], Wx[E,U], Wh[U,U], b[U]  -- ALL FLOAT32
// out = concat( output[B,T,U], state[B,U] )  float32
// B=64 T=512 U=1024 E=256
// Precision: fp16 two-way split (hi + 2^11-scaled lo), 3 MFMA products.
// This round: fully-coalesced h exchange. h is published in a fragment-ready
// packed layout (half idx = ((w*8+ki)*64+lane)*8+j2 per group) so consumer
// A-frag loads are 16B/lane contiguous (1KB/wave-instr) instead of 64
// scattered dwords; publish is one coalesced 16B sc1 store per thread via an
// LDS pack stage; xin read and out writes are coalesced dwordx4. Sync stays
// relaxed agent atomics (sc0 sc1), no fences.

#define B_ 64
#define T_ 512
#define U_ 1024
#define E_ 256
#define BTU_ (B_*T_*U_)
#define LO_SCALE 2048.0f
#define LO_INV   (1.0f/2048.0f)

typedef __attribute__((ext_vector_type(8))) _Float16 f16x8;  // MFMA A/B frag (4 VGPRs)
typedef __attribute__((ext_vector_type(4))) float f32x4;     // MFMA C/D frag

__device__ __forceinline__ void split16(float v, _Float16& hi, _Float16& lo) {
    hi = (_Float16)v;
    lo = (_Float16)((v - (float)hi) * LO_SCALE);   // scaled into fp16 normal range
}

// ---------------------------------------------------------------------------
// init: split f32 hidden into packed fp16 hi / scaled-lo planes (h_{-1}).
// pack half-index for (group g, row r=0..15, col u=0..1023):
//   g*16384 + ((u>>8)*8 + ((u>>5)&7))*512 + ((u>>3)&3)*128 + r*8 + (u&7)
// ---------------------------------------------------------------------------
__global__ void init_h(const float* __restrict__ hidden,
                       _Float16* __restrict__ hi, _Float16* __restrict__ lo)
{
    const int i = blockIdx.x * 256 + threadIdx.x;   // 0 .. B*U-1
    const int b = i >> 10, u = i & 1023;
    const int g = b >> 4, r = b & 15;
    _Float16 h, l;
    split16(hidden[i], h, l);
    const int idx = g*16384 + ((((u>>8)<<3) + ((u>>5)&7)) << 9)
                  + (((u>>3)&3) << 7) + (r << 3) + (u & 7);
    hi[idx] = h; lo[idx] = l;
}

// ---------------------------------------------------------------------------
// Phase 1: xin[m][u] = emb[x[m]][:] @ Wx + b  (m = b*T + t), f32 -> out[m*U+u]
// fp16-split MFMA (hh + cross/2048). Grid (32,16) x 256.  (unchanged)
// ---------------------------------------------------------------------------
__global__ __launch_bounds__(256, 1) void xin_gemm(
    const int* __restrict__ x, const float* __restrict__ emb,
    const float* __restrict__ Wx, const float* __restrict__ bias,
    float* __restrict__ out)
{
    const int tid  = threadIdx.x;
    const int wave = tid >> 6, lane = tid & 63;
    const int quad = lane >> 4, l15 = lane & 15;
    const int nbase  = blockIdx.y * 64;
    const int mouter = blockIdx.x * 1024;

    f16x8 b1[4][8], b2[4][8];
#pragma unroll
    for (int nt = 0; nt < 4; ++nt) {
        const int col = nbase + nt*16 + l15;
#pragma unroll
        for (int ki = 0; ki < 8; ++ki) {
            const int kb = ki*32 + quad*8;
#pragma unroll
            for (int j = 0; j < 8; ++j) {
                _Float16 h, l;
                split16(Wx[(kb + j)*U_ + col], h, l);
                b1[nt][ki][j] = h; b2[nt][ki][j] = l;
            }
        }
    }
    float bv[4];
#pragma unroll
    for (int nt = 0; nt < 4; ++nt) bv[nt] = bias[nbase + nt*16 + l15];

    const f32x4 z4 = {0.f, 0.f, 0.f, 0.f};
    for (int mc = 0; mc < 8; ++mc) {
        const int mb0 = mouter + mc*128 + wave*32;
#pragma unroll
        for (int mt = 0; mt < 2; ++mt) {
            const int tok = x[mb0 + mt*16 + l15];
            const float* ap = emb + (size_t)tok*E_ + quad*8;
            f16x8 a1[8], a2[8];
#pragma unroll
            for (int ki = 0; ki < 8; ++ki) {
                const f32x4 v0 = *(const f32x4*)(ap + ki*32);
                const f32x4 v1 = *(const f32x4*)(ap + ki*32 + 4);
#pragma unroll
                for (int j = 0; j < 4; ++j) {
                    _Float16 h, l;
                    split16(v0[j], h, l); a1[ki][j]   = h; a2[ki][j]   = l;
                    split16(v1[j], h, l); a1[ki][j+4] = h; a2[ki][j+4] = l;
                }
            }
            f32x4 acc[4]  = {z4, z4, z4, z4};
            f32x4 accX[4] = {z4, z4, z4, z4};
#pragma unroll
            for (int ki = 0; ki < 8; ++ki)
#pragma unroll
                for (int nt = 0; nt < 4; ++nt) {
                    acc[nt]  = __builtin_amdgcn_mfma_f32_16x16x32_f16(a1[ki], b1[nt][ki], acc[nt], 0, 0, 0);
                    accX[nt] = __builtin_amdgcn_mfma_f32_16x16x32_f16(a1[ki], b2[nt][ki], accX[nt], 0, 0, 0);
                    accX[nt] = __builtin_amdgcn_mfma_f32_16x16x32_f16(a2[ki], b1[nt][ki], accX[nt], 0, 0, 0);
                }
            const int rowb = mb0 + mt*16 + quad*4;
#pragma unroll
            for (int nt = 0; nt < 4; ++nt) {
                const int col = nbase + nt*16 + l15;
#pragma unroll
                for (int r = 0; r < 4; ++r)
                    out[(size_t)(rowb + r)*U_ + col] = acc[nt][r] + LO_INV*accX[nt][r] + bv[nt];
            }
        }
    }
}

// ---------------------------------------------------------------------------
// Phase 2: persistent RNN scan, fp16-split recurrence, coalesced exchange.
// 4 batch-groups x 16 blocks (64 u-cols each). Wave w owns K-range [w*256,+256).
// ---------------------------------------------------------------------------
__global__ __launch_bounds__(256, 1) void rnn_scan(
    const float* __restrict__ Wh,
    float* __restrict__ out,
    _Float16* __restrict__ hi0, _Float16* __restrict__ lo0,
    _Float16* __restrict__ hi1, _Float16* __restrict__ lo1,
    int* __restrict__ flags)
{
    const int tid  = threadIdx.x;
    const int w    = tid >> 6, lane = tid & 63;
    const int quad = lane >> 4, l15 = lane & 15;
    const int g    = blockIdx.x >> 4;    // batch group 0..3
    const int blk  = blockIdx.x & 15;    // column block 0..15
    const int bbase = g * 16;
    const int nb    = blk * 64;
    int* gflags = flags + g * 32;

    __shared__ __align__(16) float red[4][4][16][20];   // [wave][ntile][row][col(+pad)]
    __shared__ __align__(16) _Float16 pkh[1024];        // block's hi pack slice (2 KB)
    __shared__ __align__(16) _Float16 pkl[1024];        // block's lo pack slice (2 KB)

    // Persistent Wh fragments (split): k = w*256 + ki*32 + quad*8 + j, n = nb + nt*16 + l15
    f16x8 bh[4][8], bl[4][8];
#pragma unroll
    for (int nt = 0; nt < 4; ++nt) {
        const int col = nb + nt*16 + l15;
#pragma unroll
        for (int ki = 0; ki < 8; ++ki) {
            const int kb = w*256 + ki*32 + quad*8;
#pragma unroll
            for (int j = 0; j < 8; ++j) {
                _Float16 h, l;
                split16(Wh[(size_t)(kb + j)*U_ + col], h, l);
                bh[nt][ki][j] = h; bl[nt][ki][j] = l;
            }
        }
    }

    // combine-phase mapping: thread -> (batch row cb, col quad cq)
    const int cb = tid >> 4;          // 0..15
    const int cq = tid & 15;          // cols nb + cq*4 .. +3
    const int nt_c = cq >> 2;         // red ntile
    const int co_c = (cq & 3) * 4;    // red col offset
    // pack half offset within block slice for this thread's 4 h values (8B)
    const int pk_half = ((((cq>>3)<<6) + (((cq>>1)&3)<<4) + cb) << 3) + ((cq&1)<<2);

    // publish mapping: 1 x 16B per thread (threads 0-127 hi, 128-255 lo)
    const int sp_plane = tid >> 7;
    const int sp_slot  = tid & 127;

    // frag-load base offset in halves (+ ki*512)
    const size_t fl_off = (size_t)g*16384 + (size_t)w*4096 + (size_t)lane*8;

    const f32x4 z4 = {0.f, 0.f, 0.f, 0.f};

    for (int t = 0; t < T_; ++t) {
        const _Float16* chi = (t & 1) ? hi1 : hi0;
        const _Float16* clo = (t & 1) ? lo1 : lo0;
        _Float16* nhi = (t & 1) ? hi0 : hi1;
        _Float16* nlo = (t & 1) ? lo0 : lo1;

        // Coalesced L1/L2-bypass fragment loads of h_{t-1}: 16 x dwordx4/lane,
        // each wave-instruction reads a contiguous 1KB pack region.
        const _Float16* ph = chi + fl_off;
        const _Float16* pl = clo + fl_off;
        f16x8 ah[8], al[8];
#pragma unroll
        for (int ki = 0; ki < 8; ++ki) {
            f32x4 th, tl;
            asm volatile("global_load_dwordx4 %0, %1, off sc0 sc1"
                         : "=v"(th) : "v"(ph + ki*512));
            asm volatile("global_load_dwordx4 %0, %1, off sc0 sc1"
                         : "=v"(tl) : "v"(pl + ki*512));
            ah[ki] = __builtin_bit_cast(f16x8, th);
            al[ki] = __builtin_bit_cast(f16x8, tl);
        }
        // xin for this step (normal cached, coalesced dwordx4; same thread
        // later overwrites the same 16B with h_t -> no cross-thread hazard)
        float* xp = &out[((size_t)(bbase + cb)*T_ + t)*U_ + nb + cq*4];
        const f32x4 xin_v = *(const f32x4*)xp;

        asm volatile("s_waitcnt vmcnt(0)" ::: "memory");
        __builtin_amdgcn_sched_barrier(0);   // keep MFMA below the wait (rule #18)

        f32x4 acc[4]  = {z4, z4, z4, z4};
        f32x4 accX[4] = {z4, z4, z4, z4};
#pragma unroll
        for (int ki = 0; ki < 8; ++ki)
#pragma unroll
            for (int nt = 0; nt < 4; ++nt) {
                acc[nt]  = __builtin_amdgcn_mfma_f32_16x16x32_f16(ah[ki], bh[nt][ki], acc[nt], 0, 0, 0);
                accX[nt] = __builtin_amdgcn_mfma_f32_16x16x32_f16(ah[ki], bl[nt][ki], accX[nt], 0, 0, 0);
                accX[nt] = __builtin_amdgcn_mfma_f32_16x16x32_f16(al[ki], bh[nt][ki], accX[nt], 0, 0, 0);
            }
        // red layout [row][col]: combiner reads contiguous 4-col f32x4
#pragma unroll
        for (int nt = 0; nt < 4; ++nt)
#pragma unroll
            for (int r = 0; r < 4; ++r)
                red[w][nt][quad*4 + r][l15] = acc[nt][r] + LO_INV*accX[nt][r];
        __syncthreads();

        // Combine 4 k-partials, add xin, tanh
        const f32x4 s0 = *(const f32x4*)&red[0][nt_c][cb][co_c];
        const f32x4 s1 = *(const f32x4*)&red[1][nt_c][cb][co_c];
        const f32x4 s2 = *(const f32x4*)&red[2][nt_c][cb][co_c];
        const f32x4 s3 = *(const f32x4*)&red[3][nt_c][cb][co_c];
        const f32x4 pre = xin_v + ((s0 + s1) + (s2 + s3));
        f32x4 h4;
#pragma unroll
        for (int j = 0; j < 4; ++j) {
            // tanh(x) = 1 - 2/(e^{2x}+1); saturates correctly at +/-1 (inf/0 safe)
            const float e = __expf(2.0f * pre[j]);
            h4[j] = 1.0f - 2.0f * __builtin_amdgcn_rcpf(e + 1.0f);
        }
        *(f32x4*)xp = h4;   // coalesced h_t store (overwrites xin slice)

        if (t == T_ - 1) {
            *(f32x4*)&out[(size_t)BTU_ + (size_t)(bbase + cb)*U_ + nb + cq*4] = h4;
        } else {
            // stage split h into LDS in pack layout (2 x 8B ds_write)
            union { _Float16 h[4]; unsigned long long v; } uh, ul;
#pragma unroll
            for (int j = 0; j < 4; ++j) split16(h4[j], uh.h[j], ul.h[j]);
            *(unsigned long long*)&pkh[pk_half] = uh.v;
            *(unsigned long long*)&pkl[pk_half] = ul.v;
            __syncthreads();

            // coalesced MALL publish: block slice is contiguous 2KB/plane
            const f16x8 pv = *(const f16x8*)((sp_plane ? pkl : pkh) + sp_slot*8);
            _Float16* dst = (sp_plane ? nlo : nhi)
                          + (size_t)g*16384 + blk*1024 + sp_slot*8;
            asm volatile("global_store_dwordx4 %0, %1, off sc0 sc1"
                         :: "v"(dst), "v"(__builtin_bit_cast(f32x4, pv)));
            // explicit drain: compiler's barrier-drain doesn't track asm VMEM
            asm volatile("s_waitcnt vmcnt(0)" ::: "memory");
            __syncthreads();   // all waves' h published before flag

            if (tid == 0)
                __hip_atomic_store(&gflags[blk], t + 1, __ATOMIC_RELAXED, __HIP_MEMORY_SCOPE_AGENT);
            // every wave polls (no release barrier needed afterwards)
            const int tgt = t + 1;
            for (;;) {
                int fv = __hip_atomic_load(&gflags[l15], __ATOMIC_RELAXED, __HIP_MEMORY_SCOPE_AGENT);
                if (__all(fv >= tgt)) break;
                __builtin_amdgcn_s_sleep(1);
            }
            __builtin_amdgcn_sched_barrier(0);
        }
    }
}

extern "C" void kernel_launch(void* const* d_in, const int* in_sizes, int n_in,
                              void* d_out, int out_size, void* d_ws, size_t ws_size,
                              hipStream_t stream) {
    const int*   x      = (const int*)  d_in[0];
    const float* hidden = (const float*)d_in[1];
    const float* emb    = (const float*)d_in[2];
    const float* Wx     = (const float*)d_in[3];
    const float* Wh     = (const float*)d_in[4];
    const float* bias   = (const float*)d_in[5];
    float* out = (float*)d_out;

    char* ws = (char*)d_ws;
    int* flags = (int*)ws;                               // 4 groups x 32 ints
    const size_t HS = (size_t)B_ * U_ * sizeof(_Float16);   // 128 KB per plane
    _Float16* hi0 = (_Float16*)(ws + 4096);
    _Float16* lo0 = (_Float16*)(ws + 4096 + HS);
    _Float16* hi1 = (_Float16*)(ws + 4096 + 2*HS);
    _Float16* lo1 = (_Float16*)(ws + 4096 + 3*HS);

    hipMemsetAsync(ws, 0, 4096, stream);                 // barrier flags
    init_h<<<256, 256, 0, stream>>>(hidden, hi0, lo0);   // h_{-1} packed split
    xin_gemm<<<dim3(32, 16), 256, 0, stream>>>(x, emb, Wx, bias, out);
    rnn_scan<<<64, 256, 0, stream>>>(Wh, out, hi0, lo0, hi1, lo1, flags);
}